// Round 4
// baseline (30.308 us; speedup 1.0000x reference)
//
#include <hip/hip_runtime.h>

// Volume rendering: M=65536 rays, N=128 samples/ray.
// 4 rays per 64-lane wave: 16 lanes/ray, 8 samples/lane -> all loads dwordx4,
// half the cross-lane (scan/reduce) and exp work per byte vs 32-lane version.
// weights w_i = T_i - T_{i+1}, T_i = exp(-exclusive_cumsum(tau)).
//
// NOTE: exclusive scan MUST be shfl_up(inclusive, 1), not (inclusive - local):
// the terminal tau = density*1e10 (~2e10) absorbs the finite prefix in fp32.

#define NSAMP 128

__global__ __launch_bounds__(256) void volrend_kernel(
    const float* __restrict__ density,   // [M,N]
    const float* __restrict__ feature,   // [M,N,3]
    const float* __restrict__ depth,     // [M,N]
    float* __restrict__ out,             // [M,4]
    int M)
{
    const int tid = blockIdx.x * blockDim.x + threadIdx.x;
    const int ray = tid >> 4;              // one 16-lane segment per ray
    const int sub = threadIdx.x & 15;
    if (ray >= M) return;

    const int s0 = 8 * sub;                // this lane's first sample

    // ---- coalesced 16B vector loads ----
    const size_t rowN = (size_t)ray * NSAMP;
    float4 da = *(const float4*)(depth   + rowN + s0);      // d[s0..s0+3]
    float4 db = *(const float4*)(depth   + rowN + s0 + 4);  // d[s0+4..s0+7]
    float4 sa = *(const float4*)(density + rowN + s0);
    float4 sb = *(const float4*)(density + rowN + s0 + 4);
    const float* fbase = feature + (size_t)ray * NSAMP * 3 + (size_t)s0 * 3; // 96B/lane
    float4 f0 = *(const float4*)(fbase + 0);    // s0.rgb s1.r
    float4 f1 = *(const float4*)(fbase + 4);    // s1.gb  s2.rg
    float4 f2 = *(const float4*)(fbase + 8);    // s2.b   s3.rgb
    float4 f3 = *(const float4*)(fbase + 12);   // s4.rgb s5.r
    float4 f4 = *(const float4*)(fbase + 16);   // s5.gb  s6.rg
    float4 f5 = *(const float4*)(fbase + 20);   // s6.b   s7.rgb

    // ---- deltas (terminal delta = 1e10) ----
    float nx = __shfl_down(da.x, 1, 16);        // depth[s0+8] from next lane
    float t0 = sa.x * (da.y - da.x);
    float t1 = sa.y * (da.z - da.y);
    float t2 = sa.z * (da.w - da.z);
    float t3 = sa.w * (db.x - da.w);
    float t4 = sb.x * (db.y - db.x);
    float t5 = sb.y * (db.z - db.y);
    float t6 = sb.z * (db.w - db.z);
    float t7 = sb.w * ((sub == 15) ? 1e10f : (nx - db.w));

    float psum = ((t0 + t1) + (t2 + t3)) + ((t4 + t5) + (t6 + t7));

    // ---- inclusive segmented scan (width 16, 4 steps) ----
    float v = psum;
    #pragma unroll
    for (int off = 1; off < 16; off <<= 1) {
        float t = __shfl_up(v, off, 16);
        if (sub >= off) v += t;
    }
    // exact exclusive scan: previous lane's inclusive value (no cancellation)
    float excl = __shfl_up(v, 1, 16);
    if (sub == 0) excl = 0.0f;

    // cumulative optical depth at sample boundaries
    float c0 = excl;
    float c1 = c0 + t0;
    float c2 = c1 + t1;
    float c3 = c2 + t2;
    float c4 = c3 + t3;
    float c5 = c4 + t4;
    float c6 = c5 + t5;
    float c7 = c6 + t6;
    float c8 = c7 + t7;                        // lane 15: huge -> T8 = 0 exactly
    float T0 = __expf(-c0), T1 = __expf(-c1), T2 = __expf(-c2);
    float T3 = __expf(-c3), T4 = __expf(-c4), T5 = __expf(-c5);
    float T6 = __expf(-c6), T7 = __expf(-c7), T8 = __expf(-c8);
    float w0 = T0 - T1, w1 = T1 - T2, w2 = T2 - T3, w3 = T3 - T4;
    float w4 = T4 - T5, w5 = T5 - T6, w6 = T6 - T7, w7 = T7 - T8;

    // ---- weighted accumulation (8 samples) ----
    float r  = w0*f0.x + w1*f0.w + w2*f1.z + w3*f2.y
             + w4*f3.x + w5*f3.w + w6*f4.z + w7*f5.y;
    float g  = w0*f0.y + w1*f1.x + w2*f1.w + w3*f2.z
             + w4*f3.y + w5*f4.x + w6*f4.w + w7*f5.z;
    float b  = w0*f0.z + w1*f1.y + w2*f2.x + w3*f2.w
             + w4*f3.z + w5*f4.y + w6*f5.x + w7*f5.w;
    float dd = w0*da.x + w1*da.y + w2*da.z + w3*da.w
             + w4*db.x + w5*db.y + w6*db.z + w7*db.w;

    // ---- segmented reduction (width 16, 4 steps) ----
    #pragma unroll
    for (int off = 8; off >= 1; off >>= 1) {
        r  += __shfl_down(r,  off, 16);
        g  += __shfl_down(g,  off, 16);
        b  += __shfl_down(b,  off, 16);
        dd += __shfl_down(dd, off, 16);
    }

    if (sub == 0) {
        *(float4*)(out + (size_t)ray * 4) = make_float4(r, g, b, dd);
    }
}

extern "C" void kernel_launch(void* const* d_in, const int* in_sizes, int n_in,
                              void* d_out, int out_size, void* d_ws, size_t ws_size,
                              hipStream_t stream) {
    const float* density = (const float*)d_in[0];   // [M,N,1]
    const float* feature = (const float*)d_in[1];   // [M,N,3]
    const float* depth   = (const float*)d_in[2];   // [M,N]
    float* out = (float*)d_out;

    const int M = in_sizes[2] / NSAMP;              // 65536

    const int threads = 256;                        // 16 rays / block (16 lanes each)
    const int raysPerBlock = threads / 16;
    const int blocks = (M + raysPerBlock - 1) / raysPerBlock;
    volrend_kernel<<<blocks, threads, 0, stream>>>(density, feature, depth, out, M);
}

// Round 5
// 29.487 us; speedup vs baseline: 1.0278x; 1.0278x over previous
//
#include <hip/hip_runtime.h>

// Volume rendering: M=65536 rays, N=128 samples/ray.
// Round-5 restructure: ALL global loads are lane-contiguous (coalesced).
//  - wave = 2 rays; 32 lanes per ray, 4 samples per lane.
//  - density/depth: 64 lanes read 64 consecutive float4 (2 rays x 32 f4).
//  - feature: wave loads its 2 rays' 192 consecutive float4 (3/lane) into
//    regs, stages into LDS with ray stride 97 f4 (+1 pad -> all b128 LDS
//    accesses hit exactly 8 lanes/bank-quad = conflict-free), reads back
//    own-sample fragments. Weights stay in registers (same lane owns the
//    same 4 samples in both phases). No __syncthreads (wave-private LDS).
//
// NOTE: exclusive scan MUST be shfl_up(inclusive, 1), not (inclusive - local):
// the terminal tau = density*1e10 (~2e10) absorbs the finite prefix in fp32.

#define NSAMP 128
#define RAYS_PER_WAVE 2
#define WAVES_PER_BLOCK 4
#define RAYS_PER_BLOCK 8
#define FEAT_F4_STRIDE 97   // 96 f4 per ray + 1 pad f4

__global__ __launch_bounds__(256) void volrend_kernel(
    const float* __restrict__ density,   // [M,N]
    const float* __restrict__ feature,   // [M,N,3]
    const float* __restrict__ depth,     // [M,N]
    float* __restrict__ out,             // [M,4]
    int M)
{
    __shared__ float4 feat_lds[RAYS_PER_BLOCK * FEAT_F4_STRIDE];

    const int L    = threadIdx.x & 63;    // lane in wave
    const int wv   = threadIdx.x >> 6;    // wave in block
    const int sub  = L & 31;              // lane within 32-lane segment
    const int half = L >> 5;              // which of the wave's 2 rays

    const int ray0 = blockIdx.x * RAYS_PER_BLOCK + wv * RAYS_PER_WAVE;
    const int ray  = ray0 + half;
    if (ray0 >= M) return;               // M divisible by RAYS_PER_BLOCK

    // ---------- coalesced global loads (issue dens/dep first: scan waits
    // on them with vmcnt(3) while feature loads stay in flight) ----------
    // density/depth: 64 lanes -> 64 consecutive float4 (2 rays x 512B)
    const float4* dg = (const float4*)(density + (size_t)ray0 * NSAMP);
    const float4* zg = (const float4*)(depth   + (size_t)ray0 * NSAMP);
    float4 dn = dg[L];                    // = ray's chunk `sub` (samples 4sub..4sub+3)
    float4 dz = zg[L];

    // feature: wave's 2 rays = 192 consecutive float4, 3 per lane
    const float4* fg = (const float4*)(feature + (size_t)ray0 * NSAMP * 3);
    float4 fA = fg[L];
    float4 fB = fg[64 + L];
    float4 fC = fg[128 + L];

    // ---------- tau + deltas (terminal delta = 1e10) ----------
    float nx = __shfl_down(dz.x, 1, 32);  // depth[4sub+4] from next lane
    float t0 = dn.x * (dz.y - dz.x);
    float t1 = dn.y * (dz.z - dz.y);
    float t2 = dn.z * (dz.w - dz.z);
    float t3 = dn.w * ((sub == 31) ? 1e10f : (nx - dz.w));
    float psum = (t0 + t1) + (t2 + t3);

    // ---------- width-32 inclusive scan (5 steps) ----------
    float v = psum;
    #pragma unroll
    for (int off = 1; off < 32; off <<= 1) {
        float t = __shfl_up(v, off, 32);
        if (sub >= off) v += t;
    }
    float excl = __shfl_up(v, 1, 32);     // exact exclusive scan
    if (sub == 0) excl = 0.0f;

    float c0 = excl;
    float c1 = c0 + t0;
    float c2 = c1 + t1;
    float c3 = c2 + t2;
    float c4 = c3 + t3;                   // lane 31: huge -> T4 = 0 exactly
    float T0 = __expf(-c0), T1 = __expf(-c1), T2 = __expf(-c2);
    float T3 = __expf(-c3), T4 = __expf(-c4);
    float w0 = T0 - T1, w1 = T1 - T2, w2 = T2 - T3, w3 = T3 - T4;

    float dd = w0*dz.x + w1*dz.y + w2*dz.z + w3*dz.w;

    // ---------- stage feature into LDS (wave-private region) ----------
    // global f4 i (0..191) -> ray rl = i/96, q = i%96, slot = rl*97 + q.
    {
        float4* base = feat_lds + wv * RAYS_PER_WAVE * FEAT_F4_STRIDE;
        // i = L (<96 always since L<64): rl=0, q=L
        base[L] = fA;
        // i = 64+L: rl = (64+L)>=96, q = i - 96*rl
        int i1 = 64 + L;
        int s1 = (i1 >= 96) ? (FEAT_F4_STRIDE + i1 - 96) : i1;
        base[s1] = fB;
        // i = 128+L: rl=1 always, q = 32+L
        base[FEAT_F4_STRIDE + 32 + L] = fC;
    }

    // ---------- read back own-sample fragments (conflict-free) ----------
    const float4* rbase = feat_lds + (wv * RAYS_PER_WAVE + half) * FEAT_F4_STRIDE;
    float4 g0 = rbase[3*sub + 0];   // floats 12sub+0..3
    float4 g1 = rbase[3*sub + 1];   // floats 12sub+4..7
    float4 g2 = rbase[3*sub + 2];   // floats 12sub+8..11
    // channel map (compile-time): sample 4sub+k <-> weight wk
    float r  = g0.x*w0 + g0.w*w1 + g1.z*w2 + g2.y*w3;
    float g  = g0.y*w0 + g1.x*w1 + g1.w*w2 + g2.z*w3;
    float b  = g0.z*w0 + g1.y*w1 + g2.x*w2 + g2.w*w3;

    // ---------- segmented reduction (width 32, 4 values) ----------
    #pragma unroll
    for (int off = 16; off >= 1; off >>= 1) {
        r  += __shfl_down(r,  off, 32);
        g  += __shfl_down(g,  off, 32);
        b  += __shfl_down(b,  off, 32);
        dd += __shfl_down(dd, off, 32);
    }

    if (sub == 0) {
        *(float4*)(out + (size_t)ray * 4) = make_float4(r, g, b, dd);
    }
}

extern "C" void kernel_launch(void* const* d_in, const int* in_sizes, int n_in,
                              void* d_out, int out_size, void* d_ws, size_t ws_size,
                              hipStream_t stream) {
    const float* density = (const float*)d_in[0];   // [M,N,1]
    const float* feature = (const float*)d_in[1];   // [M,N,3]
    const float* depth   = (const float*)d_in[2];   // [M,N]
    float* out = (float*)d_out;

    const int M = in_sizes[2] / NSAMP;              // 65536

    const int threads = 256;                        // 4 waves = 8 rays / block
    const int blocks = (M + RAYS_PER_BLOCK - 1) / RAYS_PER_BLOCK;
    volrend_kernel<<<blocks, threads, 0, stream>>>(density, feature, depth, out, M);
}